// Round 10
// baseline (1780.562 us; speedup 1.0000x reference)
//
#include <hip/hip_runtime.h>
#include <hip/hip_bf16.h>
#include <math.h>

#define RES   160
#define RES2  (160*160)
#define RES3  (160*160*160)
#define N_PTS 2097152
#define TG_ELEMS ((size_t)RES3 * 16)           // shorts
#define TG_BYTES (TG_ELEMS * 2)                // 131,072,000 B

// weight blob: A0 (12288 B) | A1 (32768 B) | b1p (512 B) | w2p (1536 B)
#define BLOB_BYTES  47104
#define BLOB_SHORTS 22528
#define BLOB_FLOATS 512
#define A1_OFF      12288
#define B1P_OFF     45056
#define W2P_OFF     45568

// sort workspace (after tg + blob)
#define HIST_OFF   (TG_BYTES + (size_t)BLOB_BYTES)     // 131,119,104
#define CURSOR_OFF (HIST_OFF + 1024)
#define RECS_OFF   (CURSOR_OFF + 1024)                 // 131,121,152 (32-aligned)
#define SORT_TOTAL (RECS_OFF + (size_t)N_PTS * 32)     // 198,230,016

typedef __attribute__((ext_vector_type(8)))  short s16x8;
typedef __attribute__((ext_vector_type(2)))  float f32x2;
typedef __attribute__((ext_vector_type(4)))  float f32x4;
typedef __attribute__((ext_vector_type(16))) float f32x16;
typedef __attribute__((ext_vector_type(4)))  int   i32x4;

__device__ __forceinline__ unsigned short f2bf(float x) {
    union { float f; unsigned u; } v; v.f = x;
    unsigned r = v.u + 0x7FFFu + ((v.u >> 16) & 1u);
    return (unsigned short)(r >> 16);
}
__device__ __forceinline__ unsigned cvtpk(float lo, float hi) {
    unsigned r;
    asm("v_cvt_pk_bf16_f32 %0, %1, %2" : "=v"(r) : "v"(lo), "v"(hi));
    return r;
}
__device__ __forceinline__ float bf_lo(unsigned u) {
    union { unsigned u; float f; } v; v.u = u << 16; return v.f;
}
__device__ __forceinline__ float bf_hi(unsigned u) {
    union { unsigned u; float f; } v; v.u = u & 0xFFFF0000u; return v.f;
}
__device__ __forceinline__ unsigned cvtpk_relu(float a, float b) {
    return cvtpk(fmaxf(a, 0.0f), fmaxf(b, 0.0f));
}
__device__ __forceinline__ void plswap(unsigned &a, unsigned &b) {
    asm("v_permlane32_swap_b32 %0, %1" : "+v"(a), "+v"(b));
}
__device__ __forceinline__ float sum_halves(float x) {
    unsigned a = __float_as_uint(x), b = a;
    plswap(a, b);
    return __uint_as_float(a) + __uint_as_float(b);
}
__device__ __forceinline__ f32x2 pkfma(f32x2 a, f32x2 b, f32x2 c) {
    f32x2 r;
    asm("v_pk_fma_f32 %0, %1, %2, %3" : "=v"(r) : "v"(a), "v"(b), "v"(c));
    return r;
}
__device__ __forceinline__ f32x2 pkmul(f32x2 a, f32x2 b) {
    f32x2 r;
    asm("v_pk_mul_f32 %0, %1, %2" : "=v"(r) : "v"(a), "v"(b));
    return r;
}

// x-cell key, identical clamp rules to the fused gather (locality heuristic)
__device__ __forceinline__ int xkey(float x) {
    float u = (x + 1.0f) * 79.5f;
    u = fminf(fmaxf(u, 0.0f), 159.0f);
    int i0 = (int)u;
    if (i0 > 158) i0 = 158;
    return i0;
}

// ---------- weight blob value functions ----------
__device__ __forceinline__ float blob_short_val(int i, const float* __restrict__ w0,
                                                const float* __restrict__ b0,
                                                const float* __restrict__ w1) {
    if (i < 6144) {
        int e = i & 7, s = i >> 3;
        int lo = s & 31, r = s >> 5;
        int hi = r & 1, t = r >> 1;
        int wm = t / 3, ks = t - wm * 3;
        int k = ks * 16 + hi * 8 + e, n = wm * 32 + lo;
        return k < 36 ? w0[k * 128 + n] : (k == 36 ? b0[n] : 0.0f);
    } else {
        int i2 = i - 6144;
        int e = i2 & 7, s = i2 >> 3;
        int lo = s & 31, r = s >> 5;
        int hi = r & 1, t = r >> 1;
        int wm = t >> 3, ks = t & 7;
        int k = ks * 16 + hi * 8 + e, n = wm * 32 + lo;
        return w1[k * 128 + n];
    }
}
__device__ __forceinline__ float blob_float_val(int j, const float* __restrict__ b1,
                                                const float* __restrict__ w2) {
    if (j < 128) {
        int c = j & 3, r = j >> 2, hi = r & 1, t = r >> 1;
        int g = t & 3, wm = t >> 2;
        return b1[wm * 32 + 8 * g + 4 * hi + c];
    } else {
        int j2 = j - 128;
        int c  = j2 & 3;
        int t  = j2 >> 2;
        int cc = t % 3;
        int u  = t / 3;
        int hi = u & 1, v = u >> 1;
        int g  = v & 3, wm = v >> 2;
        return w2[(wm * 32 + 8 * g + 4 * hi + c) * 3 + cc];
    }
}

// ---------------- transpose: [C,X,Y,Z] f32 -> [X,Y,Z,16] bf16 ----------------
__global__ __launch_bounds__(256) void make_tg(
    const float* __restrict__ dgrid, const float* __restrict__ cgrid,
    short* __restrict__ tg)
{
    const int v = blockIdx.x * 256 + threadIdx.x;
    float vals[13];
    #pragma unroll
    for (int c = 0; c < 12; ++c) vals[c] = cgrid[(size_t)c * RES3 + v];
    vals[12] = dgrid[v];

    i32x4 r0 = { (int)cvtpk(vals[0], vals[1]),  (int)cvtpk(vals[2],  vals[3]),
                 (int)cvtpk(vals[4], vals[5]),  (int)cvtpk(vals[6],  vals[7]) };
    i32x4 r1 = { (int)cvtpk(vals[8], vals[9]),  (int)cvtpk(vals[10], vals[11]),
                 (int)cvtpk(vals[12], 0.0f),    0 };
    *(i32x4*)&tg[(size_t)v * 16 + 0] = r0;
    *(i32x4*)&tg[(size_t)v * 16 + 8] = r1;
}

// ---------------- weight prepack ----------------
__global__ __launch_bounds__(256) void prepack(
    const float* __restrict__ w0, const float* __restrict__ b0,
    const float* __restrict__ w1, const float* __restrict__ b1,
    const float* __restrict__ w2, char* __restrict__ blob)
{
    int t = blockIdx.x * 256 + threadIdx.x;
    if (t < BLOB_SHORTS) {
        ((short*)blob)[t] = (short)f2bf(blob_short_val(t, w0, b0, w1));
    } else if (t < BLOB_SHORTS + BLOB_FLOATS) {
        int j = t - BLOB_SHORTS;
        ((float*)(blob + B1P_OFF))[j] = blob_float_val(j, b1, w2);
    }
}

// ---------------- counting sort by x-cell ----------------
__global__ __launch_bounds__(256) void hist_k(
    const float* __restrict__ pts, unsigned* __restrict__ hist)
{
    __shared__ unsigned lh[160];
    const int tid = threadIdx.x;
    if (tid < 160) lh[tid] = 0;
    __syncthreads();
    const int p = blockIdx.x * 256 + tid;
    atomicAdd(&lh[xkey(pts[p * 3])], 1u);
    __syncthreads();
    if (tid < 160) {
        unsigned c = lh[tid];
        if (c) atomicAdd(&hist[tid], c);
    }
}

__global__ void scan_k(const unsigned* __restrict__ hist, unsigned* __restrict__ cursor)
{
    if (threadIdx.x == 0) {
        unsigned acc = 0;
        for (int i = 0; i < 160; ++i) { cursor[i] = acc; acc += hist[i]; }
    }
}

__global__ __launch_bounds__(256) void scatter_k(
    const float* __restrict__ pts, const float* __restrict__ vd,
    unsigned* __restrict__ cursor, float* __restrict__ recs)
{
    const int p = blockIdx.x * 256 + threadIdx.x;
    float P0 = pts[p*3+0], P1 = pts[p*3+1], P2 = pts[p*3+2];
    float V0 = vd[p*3+0],  V1 = vd[p*3+1],  V2 = vd[p*3+2];
    const int k = xkey(P0);
    const unsigned pos = atomicAdd(&cursor[k], 1u);
    f32x4 a = { P0, P1, P2, V0 };
    f32x4 b = { V1, V2, __uint_as_float((unsigned)p), 0.0f };
    f32x4* rp = (f32x4*)recs + (size_t)pos * 2;
    rp[0] = a; rp[1] = b;
}

// ---------------- fused gather + transposed-chain MLP ----------------
// MODE: 0 = naive f32 grids, 1 = TG bf16 interleaved.  SORTED: read recs, scatter out.
template<int MODE, bool PRE, bool SORTED>
__global__ __launch_bounds__(512, 4) void dvgo_fused(
    const float* __restrict__ pts, const float* __restrict__ vdirs,
    const float* __restrict__ dgrid, const float* __restrict__ cgrid,
    const short* __restrict__ tg, const float* __restrict__ recs,
    const char* __restrict__ blob,
    const float* __restrict__ w0, const float* __restrict__ b0,
    const float* __restrict__ w1, const float* __restrict__ b1,
    const float* __restrict__ w2, const float* __restrict__ b2,
    float* __restrict__ out)
{
    __shared__ __align__(16) char smem[BLOB_BYTES];
    const int tid  = threadIdx.x;
    const int lane = tid & 63;
    const int wv   = tid >> 6;
    const int lo   = lane & 31;
    const int hi   = lane >> 5;

    // XCD-chunked swizzle (bijective: gridDim.x = 4096, %8 == 0): each XCD
    // sweeps a contiguous chunk of the sorted point range -> L2-resident slab.
    int bid = blockIdx.x;
    if (SORTED) bid = (bid & 7) * (int)(gridDim.x >> 3) + (bid >> 3);

    // ---------- stage weights ----------
    if (PRE) {
        const i32x4* src = (const i32x4*)blob;
        i32x4* dst = (i32x4*)smem;
        for (int i = tid; i < BLOB_BYTES / 16; i += 512) dst[i] = src[i];
    } else {
        for (int i = tid; i < BLOB_SHORTS; i += 512)
            ((short*)smem)[i] = (short)f2bf(blob_short_val(i, w0, b0, w1));
        for (int i = tid; i < BLOB_FLOATS; i += 512)
            ((float*)(smem + B1P_OFF))[i] = blob_float_val(i, b1, w2);
    }

    // ---------- per-thread point fetch ----------
    const int p = bid * 512 + tid;
    float P0, P1, P2, V0, V1, V2;
    unsigned oidx = 0;
    if (SORTED) {
        const f32x4* rp = (const f32x4*)recs + (size_t)p * 2;
        f32x4 ra = rp[0], rb = rp[1];
        P0 = ra[0]; P1 = ra[1]; P2 = ra[2]; V0 = ra[3];
        V1 = rb[0]; V2 = rb[1];
        oidx = __float_as_uint(rb[2]);
    } else {
        P0 = pts[p*3+0]; P1 = pts[p*3+1]; P2 = pts[p*3+2];
        V0 = vdirs[p*3+0]; V1 = vdirs[p*3+1]; V2 = vdirs[p*3+2];
    }

    int   ii[3];
    float ff[3];
    float Pv[3] = {P0, P1, P2};
    #pragma unroll
    for (int d = 0; d < 3; ++d) {
        float u = (Pv[d] + 1.0f) * 79.5f;
        u = fminf(fmaxf(u, 0.0f), 159.0f);
        int i0 = (int)u;
        if (i0 > 158) i0 = 158;
        ii[d] = i0;
        ff[d] = u - (float)i0;
    }
    const float fx = ff[0], fy = ff[1], fz = ff[2];
    const float wxy0 = (1.0f-fx)*(1.0f-fy);
    const float wxy1 = (1.0f-fx)*fy;
    const float wxy2 = fx*(1.0f-fy);
    const float wxy3 = fx*fy;

    float dens;
    float col[12];

    if (MODE == 1) {
        const int base16 = ((ii[0]*RES + ii[1])*RES + ii[2]) * 16;
        const short* q00 = tg + base16;
        const short* q01 = q00 + RES*16;
        const short* q10 = q00 + RES2*16;
        const short* q11 = q10 + RES*16;

        f32x2 cv[7];
        #pragma unroll
        for (int pr = 0; pr < 7; ++pr) cv[pr] = f32x2{0.0f, 0.0f};
        const f32x2 fzv   = { fz, fz };
        const f32x2 omfzv = { 1.0f - fz, 1.0f - fz };
        const short* qs[4] = { q00, q01, q10, q11 };
        const float  wsx[4] = { wxy0, wxy1, wxy2, wxy3 };
        #pragma unroll
        for (int cn = 0; cn < 4; ++cn) {
            const short* q = qs[cn];
            i32x4 u0 = *(const i32x4*)(q);
            i32x4 u1v = *(const i32x4*)(q + 8);
            i32x4 u2 = *(const i32x4*)(q + 16);
            i32x4 u3 = *(const i32x4*)(q + 24);
            unsigned av[8] = { (unsigned)u0[0], (unsigned)u0[1], (unsigned)u0[2], (unsigned)u0[3],
                               (unsigned)u1v[0], (unsigned)u1v[1], (unsigned)u1v[2], (unsigned)u1v[3] };
            unsigned bv[8] = { (unsigned)u2[0], (unsigned)u2[1], (unsigned)u2[2], (unsigned)u2[3],
                               (unsigned)u3[0], (unsigned)u3[1], (unsigned)u3[2], (unsigned)u3[3] };
            const f32x2 wv2 = { wsx[cn], wsx[cn] };
            #pragma unroll
            for (int pr = 0; pr < 7; ++pr) {
                f32x2 va = { bf_lo(av[pr]), bf_hi(av[pr]) };
                f32x2 vb = { bf_lo(bv[pr]), bf_hi(bv[pr]) };
                f32x2 lz = pkfma(fzv, vb, pkmul(omfzv, va));
                cv[pr] = pkfma(wv2, lz, cv[pr]);
            }
        }
        #pragma unroll
        for (int c = 0; c < 12; ++c) col[c] = (c & 1) ? cv[c >> 1].y : cv[c >> 1].x;
        dens = cv[6].x;
    } else {
        const int base = (ii[0]*RES + ii[1])*RES + ii[2];
        const int o0 = base, o1 = base + RES, o2 = base + RES2, o3 = base + RES2 + RES;
        auto tl = [&](const float* __restrict__ g) -> float {
            float a0 = g[o0], a1 = g[o0+1];
            float c0 = g[o1], c1 = g[o1+1];
            float d0 = g[o2], d1 = g[o2+1];
            float e0 = g[o3], e1 = g[o3+1];
            float v0 = a0 + fz*(a1-a0);
            float v1 = c0 + fz*(c1-c0);
            float v2 = d0 + fz*(d1-d0);
            float v3 = e0 + fz*(e1-e0);
            return wxy0*v0 + wxy1*v1 + wxy2*v2 + wxy3*v3;
        };
        dens = tl(dgrid);
        #pragma unroll
        for (int c = 0; c < 12; ++c) col[c] = tl(cgrid + (size_t)c * RES3);
    }

    // feature: [k0_view(9), v(3), sin(12), cos(12), 1(bias), 0-pad] -> K=48
    float ft[36];
    #pragma unroll
    for (int j = 0; j < 9; ++j) ft[j] = col[3+j];
    ft[9] = V0; ft[10] = V1; ft[11] = V2;
    float Vv[3] = {V0, V1, V2};
    #pragma unroll
    for (int d = 0; d < 3; ++d) {
        float s1, c1;
        __sincosf(Vv[d], &s1, &c1);
        float s2 = 2.0f*s1*c1,  c2 = __builtin_fmaf(-2.0f*s1, s1, 1.0f);
        float s4 = 2.0f*s2*c2,  c4 = __builtin_fmaf(-2.0f*s2, s2, 1.0f);
        float s8 = 2.0f*s4*c4,  c8 = __builtin_fmaf(-2.0f*s4, s4, 1.0f);
        ft[12 + d] = s1; ft[15 + d] = s2; ft[18 + d] = s4; ft[21 + d] = s8;
        ft[24 + d] = c1; ft[27 + d] = c2; ft[30 + d] = c4; ft[33 + d] = c8;
    }
    unsigned fpk[24];
    #pragma unroll
    for (int j = 0; j < 18; ++j) fpk[j] = cvtpk(ft[2*j], ft[2*j+1]);
    fpk[18] = cvtpk(1.0f, 0.0f);               // bias channel k=36
    #pragma unroll
    for (int j = 19; j < 24; ++j) fpk[j] = 0u;

    // pre-swap L0 B-fragments
    #pragma unroll
    for (int ks = 0; ks < 3; ++ks)
        #pragma unroll
        for (int d = 0; d < 4; ++d)
            plswap(fpk[ks*8 + d], fpk[ks*8 + 4 + d]);

    const float col0v = col[0], col1v = col[1], col2v = col[2];
    const float scol0 = __shfl_xor(col0v, 32, 64);
    const float scol1 = __shfl_xor(col1v, 32, 64);
    const float scol2 = __shfl_xor(col2v, 32, 64);
    const float sdens = __shfl_xor(dens,  32, 64);
    const unsigned soidx = (unsigned)__shfl_xor((int)oidx, 32, 64);
    const float b2v0 = b2[0], b2v1 = b2[1], b2v2 = b2[2];

    __syncthreads();   // weights staged; no further barriers

    const char*  a0p  = smem + lane * 16;
    const char*  a1p  = smem + A1_OFF + lane * 16;
    const float* b1ph = (const float*)(smem + B1P_OFF) + hi * 4;
    const float* w2ph = (const float*)(smem + W2P_OFF) + hi * 12;

    // ---------- per-wave MFMA: 2 point-tiles of 32 (transposed chain) ----------
    #pragma unroll
    for (int pt = 0; pt < 2; ++pt) {
        // ===== layer 0 =====
        f32x16 acc0[4];
        #pragma unroll
        for (int w = 0; w < 4; ++w)
            #pragma unroll
            for (int r = 0; r < 16; ++r) acc0[w][r] = 0.0f;

        #pragma unroll
        for (int ks = 0; ks < 3; ++ks) {
            i32x4 bi = { (int)fpk[ks*8 + 4*pt + 0], (int)fpk[ks*8 + 4*pt + 1],
                         (int)fpk[ks*8 + 4*pt + 2], (int)fpk[ks*8 + 4*pt + 3] };
            s16x8 B = __builtin_bit_cast(s16x8, bi);
            #pragma unroll
            for (int w = 0; w < 4; ++w) {
                s16x8 A = *(const s16x8*)(a0p + (w*3 + ks) * 1024);
                acc0[w] = __builtin_amdgcn_mfma_f32_32x32x16_bf16(A, B, acc0[w], 0, 0, 0);
            }
        }

        unsigned u1[4][8];
        #pragma unroll
        for (int w = 0; w < 4; ++w)
            #pragma unroll
            for (int g = 0; g < 4; ++g) {
                u1[w][2*g+0] = cvtpk_relu(acc0[w][4*g+0], acc0[w][4*g+1]);
                u1[w][2*g+1] = cvtpk_relu(acc0[w][4*g+2], acc0[w][4*g+3]);
            }

        // ===== layer 1 =====
        f32x16 acc1[4];
        #pragma unroll
        for (int w = 0; w < 4; ++w)
            #pragma unroll
            for (int g = 0; g < 4; ++g) {
                f32x4 bv = *(const f32x4*)(b1ph + (w*4 + g) * 8);
                acc1[w][4*g+0] = bv[0]; acc1[w][4*g+1] = bv[1];
                acc1[w][4*g+2] = bv[2]; acc1[w][4*g+3] = bv[3];
            }
        #pragma unroll
        for (int ks = 0; ks < 8; ++ks) {
            const int w = ks >> 1, q = 4 * (ks & 1);
            plswap(u1[w][q+0], u1[w][q+2]);
            plswap(u1[w][q+1], u1[w][q+3]);
            i32x4 bi = { (int)u1[w][q+0], (int)u1[w][q+1],
                         (int)u1[w][q+2], (int)u1[w][q+3] };
            s16x8 B = __builtin_bit_cast(s16x8, bi);
            #pragma unroll
            for (int wm = 0; wm < 4; ++wm) {
                s16x8 A = *(const s16x8*)(a1p + (wm*8 + ks) * 1024);
                acc1[wm] = __builtin_amdgcn_mfma_f32_32x32x16_bf16(A, B, acc1[wm], 0, 0, 0);
            }
        }

        // ===== layer 2 (128 -> 3) packed-f32 dot =====
        f32x2 pa0 = {0.0f, 0.0f}, pa1 = {0.0f, 0.0f}, pa2 = {0.0f, 0.0f};
        #pragma unroll
        for (int w = 0; w < 4; ++w)
            #pragma unroll
            for (int g = 0; g < 4; ++g) {
                const float* wrow = w2ph + (w*4 + g) * 24;
                f32x4 q0 = *(const f32x4*)(wrow + 0);
                f32x4 q1 = *(const f32x4*)(wrow + 4);
                f32x4 q2 = *(const f32x4*)(wrow + 8);
                f32x2 v01 = { fmaxf(acc1[w][4*g+0], 0.0f), fmaxf(acc1[w][4*g+1], 0.0f) };
                f32x2 v23 = { fmaxf(acc1[w][4*g+2], 0.0f), fmaxf(acc1[w][4*g+3], 0.0f) };
                pa0 = pkfma(v01, f32x2{q0[0], q0[1]}, pa0);
                pa0 = pkfma(v23, f32x2{q0[2], q0[3]}, pa0);
                pa1 = pkfma(v01, f32x2{q1[0], q1[1]}, pa1);
                pa1 = pkfma(v23, f32x2{q1[2], q1[3]}, pa1);
                pa2 = pkfma(v01, f32x2{q2[0], q2[1]}, pa2);
                pa2 = pkfma(v23, f32x2{q2[2], q2[3]}, pa2);
            }
        float p0 = sum_halves(pa0.x + pa0.y);
        float p1 = sum_halves(pa1.x + pa1.y);
        float p2 = sum_halves(pa2.x + pa2.y);

        const float d0 = pt ? scol0 : col0v;
        const float d1 = pt ? scol1 : col1v;
        const float d2 = pt ? scol2 : col2v;
        const float dn = pt ? sdens : dens;
        if (hi == 0) {
            float x0 = p0 + b2v0 + d0;
            float x1 = p1 + b2v1 + d1;
            float x2 = p2 + b2v2 + d2;
            f32x4 o = { 1.0f / (1.0f + __expf(-x0)),
                        1.0f / (1.0f + __expf(-x1)),
                        1.0f / (1.0f + __expf(-x2)),
                        dn };
            size_t gp;
            if (SORTED) gp = (size_t)(pt ? soidx : oidx);
            else        gp = (size_t)(bid * 512 + wv * 64 + pt * 32 + lo);
            *(f32x4*)(out + gp * 4) = o;
        }
    }
}

extern "C" void kernel_launch(void* const* d_in, const int* in_sizes, int n_in,
                              void* d_out, int out_size, void* d_ws, size_t ws_size,
                              hipStream_t stream) {
    const float* pts = (const float*)d_in[0];
    const float* vd  = (const float*)d_in[1];
    const float* dg  = (const float*)d_in[2];
    const float* cg  = (const float*)d_in[3];
    const float* w0  = (const float*)d_in[4];
    const float* b0  = (const float*)d_in[5];
    const float* w1  = (const float*)d_in[6];
    const float* b1  = (const float*)d_in[7];
    const float* w2  = (const float*)d_in[8];
    const float* b2  = (const float*)d_in[9];
    float* out = (float*)d_out;

    const int n = in_sizes[0] / 3;        // 2097152 points
    const int blocks = n / 512;           // 4096

    if (ws_size >= SORT_TOTAL) {
        short*    tg     = (short*)d_ws;
        char*     blob   = (char*)d_ws + TG_BYTES;
        unsigned* hist   = (unsigned*)((char*)d_ws + HIST_OFF);
        unsigned* cursor = (unsigned*)((char*)d_ws + CURSOR_OFF);
        float*    recs   = (float*)((char*)d_ws + RECS_OFF);

        hipMemsetAsync((char*)d_ws + HIST_OFF, 0, 1024, stream);
        make_tg<<<RES3/256, 256, 0, stream>>>(dg, cg, tg);
        prepack<<<(BLOB_SHORTS + BLOB_FLOATS + 255)/256, 256, 0, stream>>>(
            w0, b0, w1, b1, w2, blob);
        hist_k<<<n/256, 256, 0, stream>>>(pts, hist);
        scan_k<<<1, 64, 0, stream>>>(hist, cursor);
        scatter_k<<<n/256, 256, 0, stream>>>(pts, vd, cursor, recs);
        dvgo_fused<1, true, true><<<blocks, 512, 0, stream>>>(
            pts, vd, dg, cg, tg, recs, blob, w0, b0, w1, b1, w2, b2, out);
    } else if (ws_size >= TG_BYTES + BLOB_BYTES) {
        short* tg = (short*)d_ws;
        char* blob = (char*)d_ws + TG_BYTES;
        make_tg<<<RES3/256, 256, 0, stream>>>(dg, cg, tg);
        prepack<<<(BLOB_SHORTS + BLOB_FLOATS + 255)/256, 256, 0, stream>>>(
            w0, b0, w1, b1, w2, blob);
        dvgo_fused<1, true, false><<<blocks, 512, 0, stream>>>(
            pts, vd, dg, cg, tg, nullptr, blob, w0, b0, w1, b1, w2, b2, out);
    } else if (ws_size >= TG_BYTES) {
        short* tg = (short*)d_ws;
        make_tg<<<RES3/256, 256, 0, stream>>>(dg, cg, tg);
        dvgo_fused<1, false, false><<<blocks, 512, 0, stream>>>(
            pts, vd, dg, cg, tg, nullptr, nullptr, w0, b0, w1, b1, w2, b2, out);
    } else {
        dvgo_fused<0, false, false><<<blocks, 512, 0, stream>>>(
            pts, vd, dg, cg, nullptr, nullptr, nullptr, w0, b0, w1, b1, w2, b2, out);
    }
}

// Round 11
// 246.151 us; speedup vs baseline: 7.2336x; 7.2336x over previous
//
#include <hip/hip_runtime.h>
#include <hip/hip_bf16.h>
#include <math.h>

#define RES   160
#define RES2  (160*160)
#define RES3  (160*160*160)
#define TG_ELEMS ((size_t)RES3 * 16)           // shorts
#define TG_BYTES (TG_ELEMS * 2)                // 131,072,000 B

// fp8 voxel grid: 16 B per voxel [x][y][z]:
//   word0: v0,v1,v2,v3 fp8 e4m3      (view ch = cgrid ch 3..6)
//   word1: v4,v5,v6,v7 fp8           (cgrid ch 7..10)
//   word2: v8 fp8, d0 fp8, d1 fp8, d2 fp8  (cgrid ch 11; diffuse = cgrid ch 0..2)
//   word3: dens bf16 (low 16), pad
#define CG16_BYTES ((size_t)RES3 * 16)         // 65,536,000 B

// weight blob: A0 (12288 B) | A1 (32768 B) | b1p (512 B) | w2p (1536 B)
#define BLOB_BYTES  47104
#define BLOB_SHORTS 22528
#define BLOB_FLOATS 512
#define A1_OFF      12288
#define B1P_OFF     45056
#define W2P_OFF     45568

typedef __attribute__((ext_vector_type(8)))  short s16x8;
typedef __attribute__((ext_vector_type(2)))  float f32x2;
typedef __attribute__((ext_vector_type(4)))  float f32x4;
typedef __attribute__((ext_vector_type(16))) float f32x16;
typedef __attribute__((ext_vector_type(4)))  int   i32x4;

__device__ __forceinline__ unsigned short f2bf(float x) {
    union { float f; unsigned u; } v; v.f = x;
    unsigned r = v.u + 0x7FFFu + ((v.u >> 16) & 1u);
    return (unsigned short)(r >> 16);
}
__device__ __forceinline__ unsigned cvtpk(float lo, float hi) {
    unsigned r;
    asm("v_cvt_pk_bf16_f32 %0, %1, %2" : "=v"(r) : "v"(lo), "v"(hi));
    return r;
}
__device__ __forceinline__ float bf_lo(unsigned u) {
    union { unsigned u; float f; } v; v.u = u << 16; return v.f;
}
__device__ __forceinline__ float bf_hi(unsigned u) {
    union { unsigned u; float f; } v; v.u = u & 0xFFFF0000u; return v.f;
}
__device__ __forceinline__ unsigned cvtpk_relu(float a, float b) {
    return cvtpk(fmaxf(a, 0.0f), fmaxf(b, 0.0f));
}
__device__ __forceinline__ void plswap(unsigned &a, unsigned &b) {
    asm("v_permlane32_swap_b32 %0, %1" : "+v"(a), "+v"(b));
}
__device__ __forceinline__ float sum_halves(float x) {
    unsigned a = __float_as_uint(x), b = a;
    plswap(a, b);
    return __uint_as_float(a) + __uint_as_float(b);
}
__device__ __forceinline__ f32x2 pkfma(f32x2 a, f32x2 b, f32x2 c) {
    f32x2 r;
    asm("v_pk_fma_f32 %0, %1, %2, %3" : "=v"(r) : "v"(a), "v"(b), "v"(c));
    return r;
}
__device__ __forceinline__ f32x2 pkmul(f32x2 a, f32x2 b) {
    f32x2 r;
    asm("v_pk_mul_f32 %0, %1, %2" : "=v"(r) : "v"(a), "v"(b));
    return r;
}

// ---------------- fp8 e4m3 encode/decode (word-select template-constant, R9-validated) ----------------
__device__ __forceinline__ unsigned enc8_manual(float x) {
    unsigned u = __float_as_uint(x);
    unsigned s = (u >> 24) & 0x80u;
    unsigned mag = u & 0x7FFFFFFFu;
    if (mag < 0x3C800000u) return s;            // |x| < 2^-6 -> 0
    if (mag >= 0x43E00000u) return s | 0x7Eu;   // saturate to 448
    unsigned r = mag + 0x7FFFFu + ((mag >> 20) & 1u);
    return s | ((r >> 20) - 960u);              // rebias (127-7)<<3
}
__device__ __forceinline__ float dec8_manual(unsigned b) {
    unsigned s = (b & 0x80u) << 24;
    unsigned em = b & 0x7Fu;
    if (em == 0) return __uint_as_float(s);
    if (em < 8) {                                // subnormal: man * 2^-9
        float v = (float)em * 0.001953125f;
        return (b & 0x80u) ? -v : v;
    }
    return __uint_as_float(s | ((em + 960u) << 20));
}
template<bool HI>
__device__ __forceinline__ unsigned pk_enc8(float a, float b, unsigned old) {
#if __has_builtin(__builtin_amdgcn_cvt_pk_fp8_f32)
    return (unsigned)__builtin_amdgcn_cvt_pk_fp8_f32(a, b, (int)old, HI);
#else
    unsigned w = enc8_manual(a) | (enc8_manual(b) << 8);
    return HI ? ((old & 0xFFFFu) | (w << 16)) : ((old & 0xFFFF0000u) | w);
#endif
}
template<bool HI>
__device__ __forceinline__ f32x2 pk_dec8(unsigned w) {
#if __has_builtin(__builtin_amdgcn_cvt_pk_f32_fp8)
    return __builtin_amdgcn_cvt_pk_f32_fp8((int)w, HI);
#else
    unsigned h = HI ? (w >> 16) : (w & 0xFFFFu);
    return f32x2{ dec8_manual(h & 0xFFu), dec8_manual((h >> 8) & 0xFFu) };
#endif
}

// ---------- weight blob value functions ----------
__device__ __forceinline__ float blob_short_val(int i, const float* __restrict__ w0,
                                                const float* __restrict__ b0,
                                                const float* __restrict__ w1) {
    if (i < 6144) {
        int e = i & 7, s = i >> 3;
        int lo = s & 31, r = s >> 5;
        int hi = r & 1, t = r >> 1;
        int wm = t / 3, ks = t - wm * 3;
        int k = ks * 16 + hi * 8 + e, n = wm * 32 + lo;
        return k < 36 ? w0[k * 128 + n] : (k == 36 ? b0[n] : 0.0f);
    } else {
        int i2 = i - 6144;
        int e = i2 & 7, s = i2 >> 3;
        int lo = s & 31, r = s >> 5;
        int hi = r & 1, t = r >> 1;
        int wm = t >> 3, ks = t & 7;
        int k = ks * 16 + hi * 8 + e, n = wm * 32 + lo;
        return w1[k * 128 + n];
    }
}
__device__ __forceinline__ float blob_float_val(int j, const float* __restrict__ b1,
                                                const float* __restrict__ w2) {
    if (j < 128) {
        int c = j & 3, r = j >> 2, hi = r & 1, t = r >> 1;
        int g = t & 3, wm = t >> 2;
        return b1[wm * 32 + 8 * g + 4 * hi + c];
    } else {
        int j2 = j - 128;
        int c  = j2 & 3;
        int t  = j2 >> 2;
        int cc = t % 3;
        int u  = t / 3;
        int hi = u & 1, v = u >> 1;
        int g  = v & 3, wm = v >> 2;
        return w2[(wm * 32 + 8 * g + 4 * hi + c) * 3 + cc];
    }
}

// ---------------- legacy transpose (fallback): [C,X,Y,Z] f32 -> [X,Y,Z,16] bf16 ----------------
__global__ __launch_bounds__(256) void make_tg(
    const float* __restrict__ dgrid, const float* __restrict__ cgrid,
    short* __restrict__ tg)
{
    const int v = blockIdx.x * 256 + threadIdx.x;
    float vals[13];
    #pragma unroll
    for (int c = 0; c < 12; ++c) vals[c] = cgrid[(size_t)c * RES3 + v];
    vals[12] = dgrid[v];

    i32x4 r0 = { (int)cvtpk(vals[0], vals[1]),  (int)cvtpk(vals[2],  vals[3]),
                 (int)cvtpk(vals[4], vals[5]),  (int)cvtpk(vals[6],  vals[7]) };
    i32x4 r1 = { (int)cvtpk(vals[8], vals[9]),  (int)cvtpk(vals[10], vals[11]),
                 (int)cvtpk(vals[12], 0.0f),    0 };
    *(i32x4*)&tg[(size_t)v * 16 + 0] = r0;
    *(i32x4*)&tg[(size_t)v * 16 + 8] = r1;
}

// ---------------- fp8 voxel pack: [C,X,Y,Z] f32 -> [X,Y,Z] 16 B ----------------
__global__ __launch_bounds__(256) void make_cg16(
    const float* __restrict__ dgrid, const float* __restrict__ cgrid,
    char* __restrict__ cg16)
{
    const int v = blockIdx.x * 256 + threadIdx.x;
    float vals[13];
    #pragma unroll
    for (int c = 0; c < 12; ++c) vals[c] = cgrid[(size_t)c * RES3 + v];
    vals[12] = dgrid[v];

    unsigned w0 = pk_enc8<false>(vals[3], vals[4], 0u);    // v0,v1
    w0 = pk_enc8<true>(vals[5], vals[6], w0);              // v2,v3
    unsigned w1 = pk_enc8<false>(vals[7], vals[8], 0u);    // v4,v5
    w1 = pk_enc8<true>(vals[9], vals[10], w1);             // v6,v7
    unsigned w2 = pk_enc8<false>(vals[11], vals[0], 0u);   // v8, d0
    w2 = pk_enc8<true>(vals[1], vals[2], w2);              // d1, d2
    unsigned w3 = (unsigned)f2bf(vals[12]);                // dens bf16, low half

    i32x4 r = { (int)w0, (int)w1, (int)w2, (int)w3 };
    *(i32x4*)(cg16 + (size_t)v * 16) = r;
}

// ---------------- weight prepack ----------------
__global__ __launch_bounds__(256) void prepack(
    const float* __restrict__ w0, const float* __restrict__ b0,
    const float* __restrict__ w1, const float* __restrict__ b1,
    const float* __restrict__ w2, char* __restrict__ blob)
{
    int t = blockIdx.x * 256 + threadIdx.x;
    if (t < BLOB_SHORTS) {
        ((short*)blob)[t] = (short)f2bf(blob_short_val(t, w0, b0, w1));
    } else if (t < BLOB_SHORTS + BLOB_FLOATS) {
        int j = t - BLOB_SHORTS;
        ((float*)(blob + B1P_OFF))[j] = blob_float_val(j, b1, w2);
    }
}

// ---------------- fused gather + transposed-chain MLP ----------------
// MODE: 0 = naive f32 grids, 1 = TG bf16 interleaved, 2 = CG16 fp8 voxel
template<int MODE, bool PRE>
__global__ __launch_bounds__(512, 4) void dvgo_fused(
    const float* __restrict__ pts, const float* __restrict__ vdirs,
    const float* __restrict__ dgrid, const float* __restrict__ cgrid,
    const short* __restrict__ tg, const char* __restrict__ cg16,
    const char* __restrict__ blob,
    const float* __restrict__ w0, const float* __restrict__ b0,
    const float* __restrict__ w1, const float* __restrict__ b1,
    const float* __restrict__ w2, const float* __restrict__ b2,
    float* __restrict__ out)
{
    __shared__ __align__(16) char smem[BLOB_BYTES];
    const int tid  = threadIdx.x;
    const int lane = tid & 63;
    const int wv   = tid >> 6;
    const int lo   = lane & 31;
    const int hi   = lane >> 5;

    // ---------- stage weights ----------
    if (PRE) {
        const i32x4* src = (const i32x4*)blob;
        i32x4* dst = (i32x4*)smem;
        for (int i = tid; i < BLOB_BYTES / 16; i += 512) dst[i] = src[i];
    } else {
        for (int i = tid; i < BLOB_SHORTS; i += 512)
            ((short*)smem)[i] = (short)f2bf(blob_short_val(i, w0, b0, w1));
        for (int i = tid; i < BLOB_FLOATS; i += 512)
            ((float*)(smem + B1P_OFF))[i] = blob_float_val(i, b1, w2);
    }

    // ---------- per-thread gather + feature build (own point) ----------
    const int p = blockIdx.x * 512 + tid;
    float P0 = pts[p*3+0], P1 = pts[p*3+1], P2 = pts[p*3+2];
    float V0 = vdirs[p*3+0], V1 = vdirs[p*3+1], V2 = vdirs[p*3+2];

    int   ii[3];
    float ff[3];
    float Pv[3] = {P0, P1, P2};
    #pragma unroll
    for (int d = 0; d < 3; ++d) {
        float u = (Pv[d] + 1.0f) * 79.5f;
        u = fminf(fmaxf(u, 0.0f), 159.0f);
        int i0 = (int)u;
        if (i0 > 158) i0 = 158;
        ii[d] = i0;
        ff[d] = u - (float)i0;
    }
    const float fx = ff[0], fy = ff[1], fz = ff[2];
    const float wxy0 = (1.0f-fx)*(1.0f-fy);
    const float wxy1 = (1.0f-fx)*fy;
    const float wxy2 = fx*(1.0f-fy);
    const float wxy3 = fx*fy;

    float dens;
    float col[12];   // 0..2 diffuse, 3..11 view

    if (MODE == 2) {
        const size_t vidx = (size_t)(ii[0] * RES + ii[1]) * RES + ii[2];
        const char* q00 = cg16 + vidx * 16;            // (x0,y0,z0); z+1 contiguous
        const char* q01 = q00 + (size_t)RES * 16;      // y+1
        const char* q10 = q00 + (size_t)RES2 * 16;     // x+1
        const char* q11 = q10 + (size_t)RES * 16;

        f32x2 cv[7];
        #pragma unroll
        for (int pr = 0; pr < 7; ++pr) cv[pr] = f32x2{0.0f, 0.0f};
        float densacc = 0.0f;

        const char* qs[4] = { q00, q01, q10, q11 };
        const float wsx[4] = { wxy0, wxy1, wxy2, wxy3 };
        #pragma unroll
        for (int cn = 0; cn < 4; ++cn) {
            const char* q = qs[cn];
            i32x4 A = *(const i32x4*)(q);          // voxel z
            i32x4 B = *(const i32x4*)(q + 16);     // voxel z+1
            const f32x2 wv2 = { wsx[cn], wsx[cn] };

            // 6 fp8 pairs: (v0v1),(v2v3),(v4v5),(v6v7),(v8,d0),(d1,d2)
            f32x2 a, b, lz;
            a = pk_dec8<false>((unsigned)A[0]); b = pk_dec8<false>((unsigned)B[0]);
            lz = pkfma(f32x2{fz,fz}, f32x2{b.x-a.x, b.y-a.y}, a);
            cv[0] = pkfma(wv2, lz, cv[0]);
            a = pk_dec8<true >((unsigned)A[0]); b = pk_dec8<true >((unsigned)B[0]);
            lz = pkfma(f32x2{fz,fz}, f32x2{b.x-a.x, b.y-a.y}, a);
            cv[1] = pkfma(wv2, lz, cv[1]);
            a = pk_dec8<false>((unsigned)A[1]); b = pk_dec8<false>((unsigned)B[1]);
            lz = pkfma(f32x2{fz,fz}, f32x2{b.x-a.x, b.y-a.y}, a);
            cv[2] = pkfma(wv2, lz, cv[2]);
            a = pk_dec8<true >((unsigned)A[1]); b = pk_dec8<true >((unsigned)B[1]);
            lz = pkfma(f32x2{fz,fz}, f32x2{b.x-a.x, b.y-a.y}, a);
            cv[3] = pkfma(wv2, lz, cv[3]);
            a = pk_dec8<false>((unsigned)A[2]); b = pk_dec8<false>((unsigned)B[2]);
            lz = pkfma(f32x2{fz,fz}, f32x2{b.x-a.x, b.y-a.y}, a);
            cv[4] = pkfma(wv2, lz, cv[4]);
            a = pk_dec8<true >((unsigned)A[2]); b = pk_dec8<true >((unsigned)B[2]);
            lz = pkfma(f32x2{fz,fz}, f32x2{b.x-a.x, b.y-a.y}, a);
            cv[5] = pkfma(wv2, lz, cv[5]);
            // dens bf16
            float da = bf_lo((unsigned)A[3]), db = bf_lo((unsigned)B[3]);
            densacc = __builtin_fmaf(wsx[cn], __builtin_fmaf(fz, db - da, da), densacc);
        }
        col[3] = cv[0].x; col[4]  = cv[0].y;
        col[5] = cv[1].x; col[6]  = cv[1].y;
        col[7] = cv[2].x; col[8]  = cv[2].y;
        col[9] = cv[3].x; col[10] = cv[3].y;
        col[11] = cv[4].x; col[0] = cv[4].y;
        col[1] = cv[5].x; col[2]  = cv[5].y;
        dens = densacc;
    } else if (MODE == 1) {
        const int base16 = ((ii[0]*RES + ii[1])*RES + ii[2]) * 16;
        const short* q00 = tg + base16;
        const short* q01 = q00 + RES*16;
        const short* q10 = q00 + RES2*16;
        const short* q11 = q10 + RES*16;

        f32x2 cv[7];
        #pragma unroll
        for (int pr = 0; pr < 7; ++pr) cv[pr] = f32x2{0.0f, 0.0f};
        const f32x2 fzv   = { fz, fz };
        const f32x2 omfzv = { 1.0f - fz, 1.0f - fz };
        const short* qs[4] = { q00, q01, q10, q11 };
        const float  wsx[4] = { wxy0, wxy1, wxy2, wxy3 };
        #pragma unroll
        for (int cn = 0; cn < 4; ++cn) {
            const short* q = qs[cn];
            i32x4 u0 = *(const i32x4*)(q);
            i32x4 u1v = *(const i32x4*)(q + 8);
            i32x4 u2 = *(const i32x4*)(q + 16);
            i32x4 u3 = *(const i32x4*)(q + 24);
            unsigned av[8] = { (unsigned)u0[0], (unsigned)u0[1], (unsigned)u0[2], (unsigned)u0[3],
                               (unsigned)u1v[0], (unsigned)u1v[1], (unsigned)u1v[2], (unsigned)u1v[3] };
            unsigned bv[8] = { (unsigned)u2[0], (unsigned)u2[1], (unsigned)u2[2], (unsigned)u2[3],
                               (unsigned)u3[0], (unsigned)u3[1], (unsigned)u3[2], (unsigned)u3[3] };
            const f32x2 wv2 = { wsx[cn], wsx[cn] };
            #pragma unroll
            for (int pr = 0; pr < 7; ++pr) {
                f32x2 va = { bf_lo(av[pr]), bf_hi(av[pr]) };
                f32x2 vb = { bf_lo(bv[pr]), bf_hi(bv[pr]) };
                f32x2 lz = pkfma(fzv, vb, pkmul(omfzv, va));
                cv[pr] = pkfma(wv2, lz, cv[pr]);
            }
        }
        #pragma unroll
        for (int c = 0; c < 12; ++c) col[c] = (c & 1) ? cv[c >> 1].y : cv[c >> 1].x;
        dens = cv[6].x;
    } else {
        const int base = (ii[0]*RES + ii[1])*RES + ii[2];
        const int o0 = base, o1 = base + RES, o2 = base + RES2, o3 = base + RES2 + RES;
        auto tl = [&](const float* __restrict__ g) -> float {
            float a0 = g[o0], a1 = g[o0+1];
            float c0 = g[o1], c1 = g[o1+1];
            float d0 = g[o2], d1 = g[o2+1];
            float e0 = g[o3], e1 = g[o3+1];
            float v0 = a0 + fz*(a1-a0);
            float v1 = c0 + fz*(c1-c0);
            float v2 = d0 + fz*(d1-d0);
            float v3 = e0 + fz*(e1-e0);
            return wxy0*v0 + wxy1*v1 + wxy2*v2 + wxy3*v3;
        };
        dens = tl(dgrid);
        #pragma unroll
        for (int c = 0; c < 12; ++c) col[c] = tl(cgrid + (size_t)c * RES3);
    }

    // feature: [k0_view(9), v(3), sin(12), cos(12), 1(bias), 0-pad] -> K=48
    float ft[36];
    #pragma unroll
    for (int j = 0; j < 9; ++j) ft[j] = col[3+j];
    ft[9] = V0; ft[10] = V1; ft[11] = V2;
    float Vv[3] = {V0, V1, V2};
    #pragma unroll
    for (int d = 0; d < 3; ++d) {
        float s1, c1;
        __sincosf(Vv[d], &s1, &c1);
        float s2 = 2.0f*s1*c1,  c2 = __builtin_fmaf(-2.0f*s1, s1, 1.0f);
        float s4 = 2.0f*s2*c2,  c4 = __builtin_fmaf(-2.0f*s2, s2, 1.0f);
        float s8 = 2.0f*s4*c4,  c8 = __builtin_fmaf(-2.0f*s4, s4, 1.0f);
        ft[12 + d] = s1; ft[15 + d] = s2; ft[18 + d] = s4; ft[21 + d] = s8;
        ft[24 + d] = c1; ft[27 + d] = c2; ft[30 + d] = c4; ft[33 + d] = c8;
    }
    unsigned fpk[24];
    #pragma unroll
    for (int j = 0; j < 18; ++j) fpk[j] = cvtpk(ft[2*j], ft[2*j+1]);
    fpk[18] = cvtpk(1.0f, 0.0f);               // bias channel k=36
    #pragma unroll
    for (int j = 19; j < 24; ++j) fpk[j] = 0u;

    // pre-swap L0 B-fragments
    #pragma unroll
    for (int ks = 0; ks < 3; ++ks)
        #pragma unroll
        for (int d = 0; d < 4; ++d)
            plswap(fpk[ks*8 + d], fpk[ks*8 + 4 + d]);

    const float col0v = col[0], col1v = col[1], col2v = col[2];
    const float scol0 = __shfl_xor(col0v, 32, 64);
    const float scol1 = __shfl_xor(col1v, 32, 64);
    const float scol2 = __shfl_xor(col2v, 32, 64);
    const float sdens = __shfl_xor(dens,  32, 64);
    const float b2v0 = b2[0], b2v1 = b2[1], b2v2 = b2[2];

    __syncthreads();   // weights staged; no further barriers

    const char*  a0p  = smem + lane * 16;
    const char*  a1p  = smem + A1_OFF + lane * 16;
    const float* b1ph = (const float*)(smem + B1P_OFF) + hi * 4;
    const float* w2ph = (const float*)(smem + W2P_OFF) + hi * 12;

    // ---------- per-wave MFMA: 2 point-tiles of 32 (transposed chain) ----------
    #pragma unroll
    for (int pt = 0; pt < 2; ++pt) {
        // ===== layer 0 =====
        f32x16 acc0[4];
        #pragma unroll
        for (int w = 0; w < 4; ++w)
            #pragma unroll
            for (int r = 0; r < 16; ++r) acc0[w][r] = 0.0f;

        #pragma unroll
        for (int ks = 0; ks < 3; ++ks) {
            i32x4 bi = { (int)fpk[ks*8 + 4*pt + 0], (int)fpk[ks*8 + 4*pt + 1],
                         (int)fpk[ks*8 + 4*pt + 2], (int)fpk[ks*8 + 4*pt + 3] };
            s16x8 B = __builtin_bit_cast(s16x8, bi);
            #pragma unroll
            for (int w = 0; w < 4; ++w) {
                s16x8 A = *(const s16x8*)(a0p + (w*3 + ks) * 1024);
                acc0[w] = __builtin_amdgcn_mfma_f32_32x32x16_bf16(A, B, acc0[w], 0, 0, 0);
            }
        }

        unsigned u1[4][8];
        #pragma unroll
        for (int w = 0; w < 4; ++w)
            #pragma unroll
            for (int g = 0; g < 4; ++g) {
                u1[w][2*g+0] = cvtpk_relu(acc0[w][4*g+0], acc0[w][4*g+1]);
                u1[w][2*g+1] = cvtpk_relu(acc0[w][4*g+2], acc0[w][4*g+3]);
            }

        // ===== layer 1 =====
        f32x16 acc1[4];
        #pragma unroll
        for (int w = 0; w < 4; ++w)
            #pragma unroll
            for (int g = 0; g < 4; ++g) {
                f32x4 bv = *(const f32x4*)(b1ph + (w*4 + g) * 8);
                acc1[w][4*g+0] = bv[0]; acc1[w][4*g+1] = bv[1];
                acc1[w][4*g+2] = bv[2]; acc1[w][4*g+3] = bv[3];
            }
        #pragma unroll
        for (int ks = 0; ks < 8; ++ks) {
            const int w = ks >> 1, q = 4 * (ks & 1);
            plswap(u1[w][q+0], u1[w][q+2]);
            plswap(u1[w][q+1], u1[w][q+3]);
            i32x4 bi = { (int)u1[w][q+0], (int)u1[w][q+1],
                         (int)u1[w][q+2], (int)u1[w][q+3] };
            s16x8 B = __builtin_bit_cast(s16x8, bi);
            #pragma unroll
            for (int wm = 0; wm < 4; ++wm) {
                s16x8 A = *(const s16x8*)(a1p + (wm*8 + ks) * 1024);
                acc1[wm] = __builtin_amdgcn_mfma_f32_32x32x16_bf16(A, B, acc1[wm], 0, 0, 0);
            }
        }

        // ===== layer 2 (128 -> 3) packed-f32 dot =====
        f32x2 pa0 = {0.0f, 0.0f}, pa1 = {0.0f, 0.0f}, pa2 = {0.0f, 0.0f};
        #pragma unroll
        for (int w = 0; w < 4; ++w)
            #pragma unroll
            for (int g = 0; g < 4; ++g) {
                const float* wrow = w2ph + (w*4 + g) * 24;
                f32x4 q0 = *(const f32x4*)(wrow + 0);
                f32x4 q1 = *(const f32x4*)(wrow + 4);
                f32x4 q2 = *(const f32x4*)(wrow + 8);
                f32x2 v01 = { fmaxf(acc1[w][4*g+0], 0.0f), fmaxf(acc1[w][4*g+1], 0.0f) };
                f32x2 v23 = { fmaxf(acc1[w][4*g+2], 0.0f), fmaxf(acc1[w][4*g+3], 0.0f) };
                pa0 = pkfma(v01, f32x2{q0[0], q0[1]}, pa0);
                pa0 = pkfma(v23, f32x2{q0[2], q0[3]}, pa0);
                pa1 = pkfma(v01, f32x2{q1[0], q1[1]}, pa1);
                pa1 = pkfma(v23, f32x2{q1[2], q1[3]}, pa1);
                pa2 = pkfma(v01, f32x2{q2[0], q2[1]}, pa2);
                pa2 = pkfma(v23, f32x2{q2[2], q2[3]}, pa2);
            }
        float p0 = sum_halves(pa0.x + pa0.y);
        float p1 = sum_halves(pa1.x + pa1.y);
        float p2 = sum_halves(pa2.x + pa2.y);

        const float d0 = pt ? scol0 : col0v;
        const float d1 = pt ? scol1 : col1v;
        const float d2 = pt ? scol2 : col2v;
        const float dn = pt ? sdens : dens;
        if (hi == 0) {
            float x0 = p0 + b2v0 + d0;
            float x1 = p1 + b2v1 + d1;
            float x2 = p2 + b2v2 + d2;
            f32x4 o = { 1.0f / (1.0f + __expf(-x0)),
                        1.0f / (1.0f + __expf(-x1)),
                        1.0f / (1.0f + __expf(-x2)),
                        dn };
            const int gp = blockIdx.x * 512 + wv * 64 + pt * 32 + lo;
            *(f32x4*)(out + (size_t)gp * 4) = o;
        }
    }
}

extern "C" void kernel_launch(void* const* d_in, const int* in_sizes, int n_in,
                              void* d_out, int out_size, void* d_ws, size_t ws_size,
                              hipStream_t stream) {
    const float* pts = (const float*)d_in[0];
    const float* vd  = (const float*)d_in[1];
    const float* dg  = (const float*)d_in[2];
    const float* cg  = (const float*)d_in[3];
    const float* w0  = (const float*)d_in[4];
    const float* b0  = (const float*)d_in[5];
    const float* w1  = (const float*)d_in[6];
    const float* b1  = (const float*)d_in[7];
    const float* w2  = (const float*)d_in[8];
    const float* b2  = (const float*)d_in[9];
    float* out = (float*)d_out;

    const int n = in_sizes[0] / 3;        // 2097152 points
    const int blocks = n / 512;           // 4096

    if (ws_size >= CG16_BYTES + BLOB_BYTES) {
        char* cg16 = (char*)d_ws;
        char* blob = (char*)d_ws + CG16_BYTES;
        make_cg16<<<RES3/256, 256, 0, stream>>>(dg, cg, cg16);
        prepack<<<(BLOB_SHORTS + BLOB_FLOATS + 255)/256, 256, 0, stream>>>(
            w0, b0, w1, b1, w2, blob);
        dvgo_fused<2, true><<<blocks, 512, 0, stream>>>(
            pts, vd, dg, cg, nullptr, cg16, blob, w0, b0, w1, b1, w2, b2, out);
    } else if (ws_size >= TG_BYTES + BLOB_BYTES) {
        short* tg = (short*)d_ws;
        char* blob = (char*)d_ws + TG_BYTES;
        make_tg<<<RES3/256, 256, 0, stream>>>(dg, cg, tg);
        prepack<<<(BLOB_SHORTS + BLOB_FLOATS + 255)/256, 256, 0, stream>>>(
            w0, b0, w1, b1, w2, blob);
        dvgo_fused<1, true><<<blocks, 512, 0, stream>>>(
            pts, vd, dg, cg, tg, nullptr, blob, w0, b0, w1, b1, w2, b2, out);
    } else if (ws_size >= TG_BYTES) {
        short* tg = (short*)d_ws;
        make_tg<<<RES3/256, 256, 0, stream>>>(dg, cg, tg);
        dvgo_fused<1, false><<<blocks, 512, 0, stream>>>(
            pts, vd, dg, cg, tg, nullptr, nullptr, w0, b0, w1, b1, w2, b2, out);
    } else {
        dvgo_fused<0, false><<<blocks, 512, 0, stream>>>(
            pts, vd, dg, cg, nullptr, nullptr, nullptr, w0, b0, w1, b1, w2, b2, out);
    }
}